// Round 4
// baseline (442.669 us; speedup 1.0000x reference)
//
#include <hip/hip_runtime.h>
#include <hip/hip_bf16.h>
#include <stdint.h>

// ---------------------------------------------------------------------------
// GSVD layer: y = x @ (U diag(S) Vh)^T, factored as
//   t = x @ (S*Vh)^T   [M=8192, R=1024],  K=4096   (split-K=2, bf16 partials)
//   y = t @ U^T        [M=8192, O=4096],  K=1024
// bf16 MFMA (16x16x32), fp32 accumulate. XOR swizzle kills LDS bank conflicts.
// ---------------------------------------------------------------------------

typedef __attribute__((ext_vector_type(8))) __bf16 bf16x8;
typedef __attribute__((ext_vector_type(4))) float f32x4;

#define AS1(p) ((const __attribute__((address_space(1))) void*)(p))
#define AS3(p) ((__attribute__((address_space(3))) void*)(p))

static __device__ __forceinline__ unsigned short f2bf(float f) {
  union { float f; unsigned int u; } c; c.f = f;
  unsigned int u = c.u;
  return (unsigned short)((u + 0x7FFFu + ((u >> 16) & 1u)) >> 16);
}
static __device__ __forceinline__ float bf2f(unsigned short h) {
  union { unsigned int u; float f; } c; c.u = ((unsigned int)h) << 16;
  return c.f;
}

// fp32 -> bf16 cast, 4 elems/thread
__global__ void cast_bf16_k(const float* __restrict__ in,
                            unsigned short* __restrict__ out, int n4) {
  int gid = blockIdx.x * blockDim.x + threadIdx.x;
  if (gid >= n4) return;
  const float4 v = ((const float4*)in)[gid];
  ushort4 o;
  o.x = f2bf(v.x); o.y = f2bf(v.y); o.z = f2bf(v.z); o.w = f2bf(v.w);
  ((ushort4*)out)[gid] = o;
}

// Vs[r][i] = bf16(S[r] * Vh[r][i])
__global__ void scale_cast_k(const float* __restrict__ Vh,
                             const float* __restrict__ S,
                             unsigned short* __restrict__ out,
                             int n4, int din4) {
  int gid = blockIdx.x * blockDim.x + threadIdx.x;
  if (gid >= n4) return;
  float s = S[gid / din4];
  const float4 v = ((const float4*)Vh)[gid];
  ushort4 o;
  o.x = f2bf(v.x * s); o.y = f2bf(v.y * s);
  o.z = f2bf(v.z * s); o.w = f2bf(v.w * s);
  ((ushort4*)out)[gid] = o;
}

// out[i] = bf16(P0[i] + P1[i]), 8 bf16/thread (16B loads/stores)
__global__ void reduce2_bf16_k(const unsigned short* __restrict__ P0,
                               const unsigned short* __restrict__ P1,
                               unsigned short* __restrict__ out, int n8) {
  int gid = blockIdx.x * blockDim.x + threadIdx.x;
  if (gid >= n8) return;
  const uint4 a = ((const uint4*)P0)[gid];
  const uint4 b = ((const uint4*)P1)[gid];
  const unsigned short* pa = (const unsigned short*)&a;
  const unsigned short* pb = (const unsigned short*)&b;
  uint4 o;
  unsigned short* po = (unsigned short*)&o;
#pragma unroll
  for (int i = 0; i < 8; ++i) po[i] = f2bf(bf2f(pa[i]) + bf2f(pb[i]));
  ((uint4*)out)[gid] = o;
}

// ---------------------------------------------------------------------------
// C[m,n] = sum_{k in [z*Kseg, (z+1)*Kseg)} A[m,k]*B[n,k]
// A:[M,ldk] bf16 rm, B:[N,ldk] bf16 rm; C partial z at C + z*M*N.
// 128x128 tile, BK=32, 256 threads = 4 waves (2x2 of 64x64), 4x4 MFMA
// 16x16x32/wave. global_load_lds width=16 staging (m97 pattern).
// LDS chunk-XOR swizzle: LDS[r][p] holds global 8-elem chunk p ^ ((r>>1)&3)
// -> ds_read_b128 lands 2-way bank aliasing (free) instead of 8-way.
// ---------------------------------------------------------------------------
template <bool OUT_BF16>
__global__ __launch_bounds__(256)
void gemm_bt(const __bf16* __restrict__ A, const __bf16* __restrict__ B,
             void* __restrict__ C, int M, int N, int Kseg, int ldk) {
  __shared__ __bf16 As[128 * 32];
  __shared__ __bf16 Bs[128 * 32];

  const int t    = threadIdx.x;
  const int lane = t & 63;
  const int wid  = __builtin_amdgcn_readfirstlane(t >> 6);

  const int bm = blockIdx.x;
  const int bn = blockIdx.y;
  const int kbase = blockIdx.z * Kseg;

  // staging: thread t covers row (t>>2); its fixed LDS slot is chunk (t&3),
  // which by the swizzle must hold global chunk (t&3) ^ ((t>>3)&3).
  const int srow = t >> 2;
  const int scol = (((t & 3) ^ ((t >> 3) & 3)) << 3);
  const __bf16* gA = A + (size_t)(bm * 128 + srow) * ldk + kbase + scol;
  const __bf16* gB = B + (size_t)(bn * 128 + srow) * ldk + kbase + scol;
  const size_t rowskip = (size_t)64 * ldk;

  __bf16* ldsA = &As[(wid * 16) * 32];
  __bf16* ldsB = &Bs[(wid * 16) * 32];

  const int wm = (wid >> 1) * 64;
  const int wn = (wid & 1) * 64;
  const int q  = lane >> 4;        // k-chunk index
  const int lr = lane & 15;        // row (A) / col (B) within 16
  // swizzled chunk byte-offset within a row (same for all frags: wm,wn,i*16
  // are multiples of 16 so (row>>1)&3 depends only on lr)
  const int chunk = ((q ^ ((lr >> 1) & 3)) << 3);

  f32x4 acc[4][4] = {};

  for (int k0 = 0; k0 < Kseg; k0 += 32) {
    __syncthreads();
    __builtin_amdgcn_global_load_lds(AS1(gA + k0),           AS3(ldsA),           16, 0, 0);
    __builtin_amdgcn_global_load_lds(AS1(gA + k0 + rowskip), AS3(ldsA + 64 * 32), 16, 0, 0);
    __builtin_amdgcn_global_load_lds(AS1(gB + k0),           AS3(ldsB),           16, 0, 0);
    __builtin_amdgcn_global_load_lds(AS1(gB + k0 + rowskip), AS3(ldsB + 64 * 32), 16, 0, 0);
    __syncthreads();

    bf16x8 af[4], bfr[4];
#pragma unroll
    for (int i = 0; i < 4; ++i)
      af[i] = *(const bf16x8*)&As[(wm + i * 16 + lr) * 32 + chunk];
#pragma unroll
    for (int j = 0; j < 4; ++j)
      bfr[j] = *(const bf16x8*)&Bs[(wn + j * 16 + lr) * 32 + chunk];

#pragma unroll
    for (int i = 0; i < 4; ++i)
#pragma unroll
      for (int j = 0; j < 4; ++j)
        acc[i][j] = __builtin_amdgcn_mfma_f32_16x16x32_bf16(af[i], bfr[j],
                                                            acc[i][j], 0, 0, 0);
  }

  // C/D layout: col = lane&15, row = (lane>>4)*4 + reg   [m89/m91 verified]
  const int r0 = q * 4;
  const size_t zoff = (size_t)blockIdx.z * M * N;
#pragma unroll
  for (int i = 0; i < 4; ++i) {
#pragma unroll
    for (int j = 0; j < 4; ++j) {
      const int col = bn * 128 + wn + j * 16 + lr;
#pragma unroll
      for (int r = 0; r < 4; ++r) {
        const int row = bm * 128 + wm + i * 16 + r0 + r;
        const float v = acc[i][j][r];
        if (OUT_BF16) {
          ((unsigned short*)C)[zoff + (size_t)row * N + col] = f2bf(v);
        } else {
          ((float*)C)[zoff + (size_t)row * N + col] = v;
        }
      }
    }
  }
}

extern "C" void kernel_launch(void* const* d_in, const int* in_sizes, int n_in,
                              void* d_out, int out_size, void* d_ws, size_t ws_size,
                              hipStream_t stream) {
  const float* x  = (const float*)d_in[0];  // [8192,4096]
  const float* U  = (const float*)d_in[1];  // [4096,1024]
  const float* S  = (const float*)d_in[2];  // [1024]
  const float* Vh = (const float*)d_in[3];  // [1024,4096]
  float* y = (float*)d_out;                 // [8192,4096] fp32

  const int M = 8192, DIN = 4096, DOUT = 4096, R = 1024;

  char* ws = (char*)d_ws;
  unsigned short* xb = (unsigned short*)(ws);              // 67108864 B: x bf16
  unsigned short* vs = (unsigned short*)(ws + 67108864);   //  8388608 B: S*Vh
  unsigned short* ub = (unsigned short*)(ws + 75497472);   //  8388608 B: U bf16
  unsigned short* p0 = (unsigned short*)(ws + 83886080);   // 16777216 B: partial0 / tb(fallback)
  unsigned short* p1 = (unsigned short*)(ws + 100663296);  // 16777216 B: partial1 (split only)

  cast_bf16_k<<<(M * DIN / 4 + 255) / 256, 256, 0, stream>>>(x, xb, M * DIN / 4);
  cast_bf16_k<<<(DOUT * R / 4 + 255) / 256, 256, 0, stream>>>(U, ub, DOUT * R / 4);
  scale_cast_k<<<(R * DIN / 4 + 255) / 256, 256, 0, stream>>>(Vh, S, vs,
                                                              R * DIN / 4, DIN / 4);

  const bool can_split = (ws_size >= 117440512u);  // constant per session
  unsigned short* tb;
  if (can_split) {
    // t partials = x @ (S*Vh)^T over K halves : grid 64x8x2 = 1024 blocks
    gemm_bt<true><<<dim3(M / 128, R / 128, 2), 256, 0, stream>>>(
        (const __bf16*)xb, (const __bf16*)vs, p0, M, R, DIN / 2, DIN);
    // tb aliases xb's region (xb is dead after gemm1)
    tb = (unsigned short*)ws;
    reduce2_bf16_k<<<(M * R / 8 + 255) / 256, 256, 0, stream>>>(p0, p1, tb,
                                                                M * R / 8);
  } else {
    tb = p0;
    gemm_bt<true><<<dim3(M / 128, R / 128, 1), 256, 0, stream>>>(
        (const __bf16*)xb, (const __bf16*)vs, tb, M, R, DIN, DIN);
  }

  // y = t @ U^T : [8192,4096], K=1024, fp32 out  (Kseg=R, ldk=R)
  gemm_bt<false><<<dim3(M / 128, DOUT / 128, 1), 256, 0, stream>>>(
      (const __bf16*)tb, (const __bf16*)ub, y, M, DOUT, R, R);
}